// Round 6
// baseline (271.276 us; speedup 1.0000x reference)
//
#include <hip/hip_runtime.h>
#include <stdint.h>

#define B_ 4
#define D_ 256
#define N_ 4096
#define K_ 8192
#define Q_ (B_*N_)   // 16384 queries

#define KSPLIT_ 4            // K-split
#define KSLICE_ (K_/KSPLIT_) // 2048 codes per block
#define NCHUNK_ (KSLICE_/32) // 64 chunks
#define QTILE_ 256           // queries per block (4 waves x 64)

typedef __attribute__((ext_vector_type(8))) short bf16x8;
typedef __attribute__((ext_vector_type(16))) float f32x16;

__device__ __forceinline__ unsigned short f32_to_bf16(float f) {
  unsigned u = __float_as_uint(f);
  unsigned r = 0x7FFFu + ((u >> 16) & 1u);
  return (unsigned short)((u + r) >> 16);
}
__device__ __forceinline__ float bf16_to_f32(unsigned short h) {
  return __uint_as_float(((unsigned)h) << 16);
}

// async global->LDS, 16B per lane; LDS dest is wave-uniform base + lane*16
__device__ __forceinline__ void gl_lds16(const void* g, void* l) {
  __builtin_amdgcn_global_load_lds(
      (const __attribute__((address_space(1))) unsigned int*)g,
      (__attribute__((address_space(3))) unsigned int*)l, 16, 0, 0);
}

// Transpose x [B, D, N] -> xh/xl [Q=B*N, D] bf16 hi/lo split.
__global__ void prep_x_kernel(const float* __restrict__ x,
                              unsigned short* __restrict__ xh,
                              unsigned short* __restrict__ xl) {
  __shared__ float tile[32][33];
  int b = blockIdx.z;
  int d0 = blockIdx.y * 32;
  int n0 = blockIdx.x * 32;
  int tx = threadIdx.x, ty = threadIdx.y;
  const float* xp = x + ((size_t)b * D_ + d0) * N_ + n0;
#pragma unroll
  for (int i = 0; i < 4; ++i)
    tile[ty + 8 * i][tx] = xp[(size_t)(ty + 8 * i) * N_ + tx];
  __syncthreads();
#pragma unroll
  for (int i = 0; i < 4; ++i) {
    int nl = ty + 8 * i;
    float v = tile[tx][nl];
    unsigned short h = f32_to_bf16(v);
    unsigned short l = f32_to_bf16(v - bf16_to_f32(h));
    size_t q = (size_t)b * N_ + n0 + nl;
    xh[q * D_ + d0 + tx] = h;
    xl[q * D_ + d0 + tx] = l;
  }
}

// Split e [K, D] into bf16 hi/lo; compute 0.5*||e_k||^2; init keys.
__global__ void prep_e_kernel(const float* __restrict__ e,
                              unsigned short* __restrict__ eh,
                              unsigned short* __restrict__ el,
                              float* __restrict__ e2h,
                              unsigned long long* __restrict__ keys) {
  int k = blockIdx.x;
  int d = threadIdx.x;  // 256 threads
  if (d < 2) keys[(size_t)k * 2 + d] = ~0ull;  // Q_ = 2*K_
  float v = e[(size_t)k * D_ + d];
  unsigned short h = f32_to_bf16(v);
  unsigned short l = f32_to_bf16(v - bf16_to_f32(h));
  eh[(size_t)k * D_ + d] = h;
  el[(size_t)k * D_ + d] = l;
  float s = v * v;
#pragma unroll
  for (int off = 32; off > 0; off >>= 1) s += __shfl_down(s, off, 64);
  __shared__ float ws4[4];
  if ((threadIdx.x & 63) == 0) ws4[threadIdx.x >> 6] = s;
  __syncthreads();
  if (threadIdx.x == 0) e2h[k] = 0.5f * (ws4[0] + ws4[1] + ws4[2] + ws4[3]);
}

// Main R6: block = 256 queries x 2048 codes, 4 waves x 64 QUERIES PER WAVE.
// R0-R5 invariant: MfmaUtil ~50% with MFMA floor (198k cyc/CU) == LDS floor
// (197k) and zero pipe overlap under every scheduling fix tried. Fix the
// RATIO instead: M=64/wave makes each B-fragment pair (2 ds_read_b128,
// 24 cyc) feed 6 MFMAs (192 cyc) instead of 3 -> per-CU LDS traffic halves
// (128 reads/chunk vs 256). Serial floor 396k -> 296k cyc; overlap now has
// 2:1 headroom instead of 1:1 knife-edge.
// Cost: A-frags = 256 regs (2 tiles x hi/lo), total ~380 live -> 1 wave/SIMD
// at launch_bounds(256,1) (512-reg unified VGPR+AGPR budget, gfx950).
// Grid 256 = 1 block/CU. Proven R0 __syncthreads double-buffer (R5's
// counted-vmcnt asm regressed; reverted). acc0/acc1 = 2 independent chains.
// d2_hat = 0.5*e2[k] - x.e_k; running min; u64 atomicMin merge.
__global__ __launch_bounds__(256, 1) void vq_main_kernel(
    const unsigned short* __restrict__ xh, const unsigned short* __restrict__ xl,
    const unsigned short* __restrict__ eh, const unsigned short* __restrict__ el,
    const float* __restrict__ e2h, unsigned long long* __restrict__ keys) {
  // [buf][half][code*256 + swizzled runs]; 64 KB total, dense (DMA-compatible).
  // run g of code c lives at 16B-slot (g ^ (c&31)) within the code's 512 B row.
  __shared__ __attribute__((aligned(16))) unsigned short Bs[2][2][32 * 256];

  const int tid = threadIdx.x;
  const int w = tid >> 6;       // wave 0..3
  const int lane = tid & 63;
  const int l = lane & 31;      // spatial index (code col / query row)
  const int hi = lane >> 5;     // k-group half

  const int qt = blockIdx.x >> 2;
  const int ksl = blockIdx.x & 3;
  const int q0 = qt * QTILE_;
  const int kbase = ksl * KSLICE_;
  const int qw = q0 + w * 64;   // 64 queries per wave (2 M-tiles of 32)

  // Persistent A fragments: 2 tiles x 32 queries x 256 d, hi+lo.
  // A[m=lane&31][k=hi*8+j]; 64 x bf16x8 = 256 regs (allocator uses AGPRs).
  bf16x8 ah0[16], al0[16], ah1[16], al1[16];
  {
    const unsigned short* p0h = xh + (size_t)(qw + l) * D_ + hi * 8;
    const unsigned short* p0l = xl + (size_t)(qw + l) * D_ + hi * 8;
    const unsigned short* p1h = xh + (size_t)(qw + 32 + l) * D_ + hi * 8;
    const unsigned short* p1l = xl + (size_t)(qw + 32 + l) * D_ + hi * 8;
#pragma unroll
    for (int kc16 = 0; kc16 < 16; ++kc16) {
      ah0[kc16] = *(const bf16x8*)(p0h + kc16 * 16);
      al0[kc16] = *(const bf16x8*)(p0l + kc16 * 16);
      ah1[kc16] = *(const bf16x8*)(p1h + kc16 * 16);
      al1[kc16] = *(const bf16x8*)(p1l + kc16 * 16);
    }
  }

  float rminv0[16], rminv1[16];
  int rmini0[16], rmini1[16];
#pragma unroll
  for (int r = 0; r < 16; ++r) {
    rminv0[r] = __builtin_inff(); rmini0[r] = 0;
    rminv1[r] = __builtin_inff(); rmini1[r] = 0;
  }

  // Stage chunk ch into buf: wave w loads codes [w*8, w*8+8), both halves.
  // One instr = 64 lanes x 16B = 2 code rows. Swizzle via source address.
  // 8 gl_lds per wave per chunk (4 waves cover 32 codes x hi/lo).
  auto stage = [&](int ch, int buf) {
    const int kc = kbase + ch * 32;
#pragma unroll
    for (int p = 0; p < 4; ++p) {
      const int c0 = w * 8 + p * 2;
      const int c = c0 + hi;
      const int g = l ^ (c & 31);
      const size_t srcoff = (size_t)(kc + c) * D_ + g * 8;
      gl_lds16(eh + srcoff, &Bs[buf][0][c0 * 256]);
      gl_lds16(el + srcoff, &Bs[buf][1][c0 * 256]);
    }
  };

  stage(0, 0);

#pragma unroll 1
  for (int ch = 0; ch < NCHUNK_; ++ch) {
    const int buf = ch & 1;
    __syncthreads();                    // drains DMA for chunk ch (vmcnt 0)
    if (ch + 1 < NCHUNK_) stage(ch + 1, buf ^ 1);
    const int kc = kbase + ch * 32;
    const float e2v = e2h[kc + l];      // issue early; L1/L2-hot

    f32x16 acc0, acc1;
#pragma unroll
    for (int r = 0; r < 16; ++r) { acc0[r] = 0.f; acc1[r] = 0.f; }

#pragma unroll
    for (int ks = 0; ks < 16; ++ks) {
      const int pos = (((ks * 2 + hi) ^ l) * 8);
      bf16x8 bh = *(const bf16x8*)&Bs[buf][0][l * 256 + pos];
      bf16x8 bl = *(const bf16x8*)&Bs[buf][1][l * 256 + pos];
      acc0 = __builtin_amdgcn_mfma_f32_32x32x16_bf16(ah0[ks], bh, acc0, 0, 0, 0);
      acc1 = __builtin_amdgcn_mfma_f32_32x32x16_bf16(ah1[ks], bh, acc1, 0, 0, 0);
      acc0 = __builtin_amdgcn_mfma_f32_32x32x16_bf16(ah0[ks], bl, acc0, 0, 0, 0);
      acc1 = __builtin_amdgcn_mfma_f32_32x32x16_bf16(ah1[ks], bl, acc1, 0, 0, 0);
      acc0 = __builtin_amdgcn_mfma_f32_32x32x16_bf16(al0[ks], bh, acc0, 0, 0, 0);
      acc1 = __builtin_amdgcn_mfma_f32_32x32x16_bf16(al1[ks], bh, acc1, 0, 0, 0);
    }

    const int kidx = kc + l;  // all acc regs share the same code column
#pragma unroll
    for (int r = 0; r < 16; ++r) {
      float dv0 = e2v - acc0[r];
      bool b0 = dv0 < rminv0[r];
      rminv0[r] = b0 ? dv0 : rminv0[r];
      rmini0[r] = b0 ? kidx : rmini0[r];
      float dv1 = e2v - acc1[r];
      bool b1 = dv1 < rminv1[r];
      rminv1[r] = b1 ? dv1 : rminv1[r];
      rmini1[r] = b1 ? kidx : rmini1[r];
    }
  }

  // Reduce over the 32 code-columns within each half-wave (xm<=16 keeps the
  // reduction inside each 32-lane half), then cross-block merge via packed
  // (sortable-float<<32 | idx) u64 atomicMin. Two tiles.
#pragma unroll
  for (int r = 0; r < 16; ++r) {
    const int m = (r & 3) + 8 * (r >> 2) + 4 * hi;  // C/D row mapping (m74/m101)
    {
      float bv = rminv0[r];
      int bi = rmini0[r];
#pragma unroll
      for (int xm = 1; xm <= 16; xm <<= 1) {
        float ov = __shfl_xor(bv, xm, 64);
        int oi = __shfl_xor(bi, xm, 64);
        if (ov < bv || (ov == bv && oi < bi)) { bv = ov; bi = oi; }
      }
      if (l == 0) {
        unsigned su = __float_as_uint(bv);
        su ^= (unsigned)(((int)su >> 31) | 0x80000000u);
        unsigned long long key = ((unsigned long long)su << 32) | (unsigned)bi;
        atomicMin(keys + (qw + m), key);
      }
    }
    {
      float bv = rminv1[r];
      int bi = rmini1[r];
#pragma unroll
      for (int xm = 1; xm <= 16; xm <<= 1) {
        float ov = __shfl_xor(bv, xm, 64);
        int oi = __shfl_xor(bi, xm, 64);
        if (ov < bv || (ov == bv && oi < bi)) { bv = ov; bi = oi; }
      }
      if (l == 0) {
        unsigned su = __float_as_uint(bv);
        su ^= (unsigned)(((int)su >> 31) | 0x80000000u);
        unsigned long long key = ((unsigned long long)su << 32) | (unsigned)bi;
        atomicMin(keys + (qw + 32 + m), key);
      }
    }
  }
}

// Decode: out[b][d][n] = e[code[b,n]][d].
// Tiled LDS-transpose gather: reads e rows in coalesced 128B slices,
// writes out in 128B-contiguous n-runs.
__global__ void decode_kernel(const unsigned long long* __restrict__ keys,
                              const float* __restrict__ e,
                              float* __restrict__ out) {
  __shared__ float tile[32][33];
  __shared__ int codes[32];
  int b = blockIdx.y;
  int n0 = blockIdx.x * 32;
  int tx = threadIdx.x, ty = threadIdx.y;  // (32, 8)
  if (ty == 0)
    codes[tx] = (int)(keys[(size_t)b * N_ + n0 + tx] & 0xFFFFFFFFull);
  __syncthreads();
#pragma unroll 1
  for (int d0 = 0; d0 < D_; d0 += 32) {
    // gather: row nl's 32-d slice, coalesced 128B per row
#pragma unroll
    for (int i = 0; i < 4; ++i) {
      int nl = ty + 8 * i;
      tile[nl][tx] = e[(size_t)codes[nl] * D_ + d0 + tx];
    }
    __syncthreads();
    // transposed write: 32 consecutive n per instruction
#pragma unroll
    for (int i = 0; i < 4; ++i) {
      int dl = ty + 8 * i;
      out[((size_t)b * D_ + d0 + dl) * N_ + n0 + tx] = tile[tx][dl];
    }
    __syncthreads();
  }
}

extern "C" void kernel_launch(void* const* d_in, const int* in_sizes, int n_in,
                              void* d_out, int out_size, void* d_ws, size_t ws_size,
                              hipStream_t stream) {
  const float* x = (const float*)d_in[0];
  const float* e = (const float*)d_in[1];
  float* out = (float*)d_out;

  // workspace layout (~24.2 MB)
  char* wksp = (char*)d_ws;
  unsigned short* xh = (unsigned short*)wksp;                   // 8 MB
  unsigned short* xl = xh + (size_t)Q_ * D_;                    // 8 MB
  unsigned short* eh = xl + (size_t)Q_ * D_;                    // 4 MB
  unsigned short* el = eh + (size_t)K_ * D_;                    // 4 MB
  float* e2h = (float*)(el + (size_t)K_ * D_);                  // 32 KB
  unsigned long long* keys = (unsigned long long*)(e2h + K_);   // 128 KB

  prep_x_kernel<<<dim3(N_ / 32, D_ / 32, B_), dim3(32, 8), 0, stream>>>(x, xh, xl);
  prep_e_kernel<<<K_, 256, 0, stream>>>(e, eh, el, e2h, keys);
  vq_main_kernel<<<(Q_ / QTILE_) * KSPLIT_, 256, 0, stream>>>(xh, xl, eh, el, e2h, keys);
  decode_kernel<<<dim3(N_ / 32, B_), dim3(32, 8), 0, stream>>>(keys, e, out);
}

// Round 7
// 252.787 us; speedup vs baseline: 1.0731x; 1.0731x over previous
//
#include <hip/hip_runtime.h>
#include <stdint.h>

#define B_ 4
#define D_ 256
#define N_ 4096
#define K_ 8192
#define Q_ (B_*N_)   // 16384 queries

#define KSPLIT_ 4            // K-split
#define KSLICE_ (K_/KSPLIT_) // 2048 codes per block
#define CHUNK_ 64            // codes per chunk (2 x 32-code MFMA sub-tiles)
#define NCHUNK_ (KSLICE_/CHUNK_) // 32 chunks
#define QTILE_ 256           // queries per block (8 waves x 32)

typedef __attribute__((ext_vector_type(8))) short bf16x8;
typedef __attribute__((ext_vector_type(16))) float f32x16;

__device__ __forceinline__ unsigned short f32_to_bf16(float f) {
  unsigned u = __float_as_uint(f);
  unsigned r = 0x7FFFu + ((u >> 16) & 1u);
  return (unsigned short)((u + r) >> 16);
}
__device__ __forceinline__ float bf16_to_f32(unsigned short h) {
  return __uint_as_float(((unsigned)h) << 16);
}

// async global->LDS, 16B per lane; LDS dest is wave-uniform base + lane*16
__device__ __forceinline__ void gl_lds16(const void* g, void* l) {
  __builtin_amdgcn_global_load_lds(
      (const __attribute__((address_space(1))) unsigned int*)g,
      (__attribute__((address_space(3))) unsigned int*)l, 16, 0, 0);
}

// Transpose x [B, D, N] -> xh/xl [Q=B*N, D] bf16 hi/lo split of NEGATED x.
// (-x lets vq_main fold the e2 term into the MFMA C-init: acc = 0.5e2 +
// (-x).e = d2_hat directly. bf16 rounding is sign-symmetric -> numerics
// identical to negating after split.)
__global__ void prep_x_kernel(const float* __restrict__ x,
                              unsigned short* __restrict__ xh,
                              unsigned short* __restrict__ xl) {
  __shared__ float tile[32][33];
  int b = blockIdx.z;
  int d0 = blockIdx.y * 32;
  int n0 = blockIdx.x * 32;
  int tx = threadIdx.x, ty = threadIdx.y;
  const float* xp = x + ((size_t)b * D_ + d0) * N_ + n0;
#pragma unroll
  for (int i = 0; i < 4; ++i)
    tile[ty + 8 * i][tx] = xp[(size_t)(ty + 8 * i) * N_ + tx];
  __syncthreads();
#pragma unroll
  for (int i = 0; i < 4; ++i) {
    int nl = ty + 8 * i;
    float v = -tile[tx][nl];
    unsigned short h = f32_to_bf16(v);
    unsigned short l = f32_to_bf16(v - bf16_to_f32(h));
    size_t q = (size_t)b * N_ + n0 + nl;
    xh[q * D_ + d0 + tx] = h;
    xl[q * D_ + d0 + tx] = l;
  }
}

// Split e [K, D] into bf16 hi/lo; compute 0.5*||e_k||^2; init keys.
__global__ void prep_e_kernel(const float* __restrict__ e,
                              unsigned short* __restrict__ eh,
                              unsigned short* __restrict__ el,
                              float* __restrict__ e2h,
                              unsigned long long* __restrict__ keys) {
  int k = blockIdx.x;
  int d = threadIdx.x;  // 256 threads
  if (d < 2) keys[(size_t)k * 2 + d] = ~0ull;  // Q_ = 2*K_
  float v = e[(size_t)k * D_ + d];
  unsigned short h = f32_to_bf16(v);
  unsigned short l = f32_to_bf16(v - bf16_to_f32(h));
  eh[(size_t)k * D_ + d] = h;
  el[(size_t)k * D_ + d] = l;
  float s = v * v;
#pragma unroll
  for (int off = 32; off > 0; off >>= 1) s += __shfl_down(s, off, 64);
  __shared__ float ws4[4];
  if ((threadIdx.x & 63) == 0) ws4[threadIdx.x >> 6] = s;
  __syncthreads();
  if (threadIdx.x == 0) e2h[k] = 0.5f * (ws4[0] + ws4[1] + ws4[2] + ws4[3]);
}

// Main R7: R0 core (8 waves x 32 q, 2 waves/SIMD — best measured, 182 us)
// with CHUNK=64: two 32-code sub-tiles per barrier interval. Evidence R0-R6:
// MfmaUtil ~50% invariant under barrier-domain/chain/vmcnt/M changes; the
// stall is LDS round-trip latency vs register-capped B-prefetch (236/256
// regs used). Can't deepen prefetch -> amortize instead: halve the count of
// barrier/drain/acc-init/min-update events (96 MFMA per barrier vs 48).
// LDS 2x64=128 KB <= 160, 1 block/CU, same register picture as R0.
// acc is INITIALIZED to 0.5e2 (x negated in prep) so acc_final = d2_hat.
__global__ __launch_bounds__(512, 2) void vq_main_kernel(
    const unsigned short* __restrict__ xh, const unsigned short* __restrict__ xl,
    const unsigned short* __restrict__ eh, const unsigned short* __restrict__ el,
    const float* __restrict__ e2h, unsigned long long* __restrict__ keys) {
  // [buf][half][code*256 + swizzled runs]; 128 KB total, dense (DMA-ok).
  // 16B-slot s of code row c holds run g = s ^ (c&31).
  __shared__ __attribute__((aligned(16))) unsigned short Bs[2][2][CHUNK_ * 256];

  const int tid = threadIdx.x;
  const int w = tid >> 6;       // wave 0..7
  const int lane = tid & 63;
  const int l = lane & 31;      // spatial index (code col / query row)
  const int hi = lane >> 5;     // k-group half

  const int qt = blockIdx.x >> 2;
  const int ksl = blockIdx.x & 3;
  const int q0 = qt * QTILE_;
  const int kbase = ksl * KSLICE_;
  const int qw = q0 + w * 32;

  // Persistent A fragments: 32 queries x 256 d, hi+lo (of -x).
  // A[m=lane&31][k=hi*8+j]; 128 regs, allocator places in AGPRs.
  bf16x8 ah[16], al[16];
  {
    const unsigned short* pa = xh + (size_t)(qw + l) * D_ + hi * 8;
    const unsigned short* pb = xl + (size_t)(qw + l) * D_ + hi * 8;
#pragma unroll
    for (int kc16 = 0; kc16 < 16; ++kc16) {
      ah[kc16] = *(const bf16x8*)(pa + kc16 * 16);
      al[kc16] = *(const bf16x8*)(pb + kc16 * 16);
    }
  }

  float rminv[16];
  int rmini[16];
#pragma unroll
  for (int r = 0; r < 16; ++r) { rminv[r] = __builtin_inff(); rmini[r] = 0; }

  // Stage chunk ch (64 codes x hi/lo) into buf: wave w loads codes
  // [w*8, w*8+8). One instr = 64 lanes x 16B = 2 code rows, swizzled via
  // source address. 8 gl_lds per wave per chunk.
  auto stage = [&](int ch, int buf) {
    const int kc = kbase + ch * CHUNK_;
#pragma unroll
    for (int p = 0; p < 4; ++p) {
      const int c0 = w * 8 + p * 2;
      const int c = c0 + hi;
      const int g = l ^ (c & 31);
      const size_t srcoff = (size_t)(kc + c) * D_ + g * 8;
      gl_lds16(eh + srcoff, &Bs[buf][0][c0 * 256]);
      gl_lds16(el + srcoff, &Bs[buf][1][c0 * 256]);
    }
  };

  stage(0, 0);

#pragma unroll 1
  for (int ch = 0; ch < NCHUNK_; ++ch) {
    const int buf = ch & 1;
    __syncthreads();                    // drains DMA for chunk ch
    if (ch + 1 < NCHUNK_) stage(ch + 1, buf ^ 1);
    const int kc = kbase + ch * CHUNK_;
    const float e2v0 = e2h[kc + l];       // L2-hot
    const float e2v1 = e2h[kc + 32 + l];

    // ---- sub-tile 0: codes [kc, kc+32) ----
    {
      f32x16 acc;
#pragma unroll
      for (int r = 0; r < 16; ++r) acc[r] = e2v0;  // C-init = 0.5*e2
#pragma unroll
      for (int ks = 0; ks < 16; ++ks) {
        const int pos = (((ks * 2 + hi) ^ l) * 8);
        bf16x8 bh = *(const bf16x8*)&Bs[buf][0][l * 256 + pos];
        bf16x8 bl = *(const bf16x8*)&Bs[buf][1][l * 256 + pos];
        acc = __builtin_amdgcn_mfma_f32_32x32x16_bf16(ah[ks], bh, acc, 0, 0, 0);
        acc = __builtin_amdgcn_mfma_f32_32x32x16_bf16(ah[ks], bl, acc, 0, 0, 0);
        acc = __builtin_amdgcn_mfma_f32_32x32x16_bf16(al[ks], bh, acc, 0, 0, 0);
      }
      const int kidx = kc + l;
#pragma unroll
      for (int r = 0; r < 16; ++r) {
        bool better = acc[r] < rminv[r];
        rminv[r] = better ? acc[r] : rminv[r];
        rmini[r] = better ? kidx : rmini[r];
      }
    }

    // ---- sub-tile 1: codes [kc+32, kc+64) ----
    {
      f32x16 acc;
#pragma unroll
      for (int r = 0; r < 16; ++r) acc[r] = e2v1;
#pragma unroll
      for (int ks = 0; ks < 16; ++ks) {
        const int pos = (((ks * 2 + hi) ^ l) * 8);
        bf16x8 bh = *(const bf16x8*)&Bs[buf][0][(32 + l) * 256 + pos];
        bf16x8 bl = *(const bf16x8*)&Bs[buf][1][(32 + l) * 256 + pos];
        acc = __builtin_amdgcn_mfma_f32_32x32x16_bf16(ah[ks], bh, acc, 0, 0, 0);
        acc = __builtin_amdgcn_mfma_f32_32x32x16_bf16(ah[ks], bl, acc, 0, 0, 0);
        acc = __builtin_amdgcn_mfma_f32_32x32x16_bf16(al[ks], bh, acc, 0, 0, 0);
      }
      const int kidx = kc + 32 + l;
#pragma unroll
      for (int r = 0; r < 16; ++r) {
        bool better = acc[r] < rminv[r];
        rminv[r] = better ? acc[r] : rminv[r];
        rmini[r] = better ? kidx : rmini[r];
      }
    }
  }

  // Reduce over the 32 code-columns within each half-wave, then cross-block
  // merge via packed (sortable-float<<32 | idx) u64 atomicMin.
#pragma unroll
  for (int r = 0; r < 16; ++r) {
    float bv = rminv[r];
    int bi = rmini[r];
#pragma unroll
    for (int xm = 1; xm <= 16; xm <<= 1) {
      float ov = __shfl_xor(bv, xm, 64);
      int oi = __shfl_xor(bi, xm, 64);
      if (ov < bv || (ov == bv && oi < bi)) { bv = ov; bi = oi; }
    }
    if (l == 0) {
      const int m = (r & 3) + 8 * (r >> 2) + 4 * hi;  // C/D row mapping (m74/m101)
      const int qq = qw + m;
      unsigned su = __float_as_uint(bv);
      su ^= (unsigned)(((int)su >> 31) | 0x80000000u);
      unsigned long long key = ((unsigned long long)su << 32) | (unsigned)bi;
      atomicMin(keys + qq, key);
    }
  }
}

// Decode: out[b][d][n] = e[code[b,n]][d].
// Tiled LDS-transpose gather: reads e rows in coalesced 128B slices,
// writes out in 128B-contiguous n-runs.
__global__ void decode_kernel(const unsigned long long* __restrict__ keys,
                              const float* __restrict__ e,
                              float* __restrict__ out) {
  __shared__ float tile[32][33];
  __shared__ int codes[32];
  int b = blockIdx.y;
  int n0 = blockIdx.x * 32;
  int tx = threadIdx.x, ty = threadIdx.y;  // (32, 8)
  if (ty == 0)
    codes[tx] = (int)(keys[(size_t)b * N_ + n0 + tx] & 0xFFFFFFFFull);
  __syncthreads();
#pragma unroll 1
  for (int d0 = 0; d0 < D_; d0 += 32) {
    // gather: row nl's 32-d slice, coalesced 128B per row
#pragma unroll
    for (int i = 0; i < 4; ++i) {
      int nl = ty + 8 * i;
      tile[nl][tx] = e[(size_t)codes[nl] * D_ + d0 + tx];
    }
    __syncthreads();
    // transposed write: 32 consecutive n per instruction
#pragma unroll
    for (int i = 0; i < 4; ++i) {
      int dl = ty + 8 * i;
      out[((size_t)b * D_ + d0 + dl) * N_ + n0 + tx] = tile[tx][dl];
    }
    __syncthreads();
  }
}

extern "C" void kernel_launch(void* const* d_in, const int* in_sizes, int n_in,
                              void* d_out, int out_size, void* d_ws, size_t ws_size,
                              hipStream_t stream) {
  const float* x = (const float*)d_in[0];
  const float* e = (const float*)d_in[1];
  float* out = (float*)d_out;

  // workspace layout (~24.2 MB)
  char* wksp = (char*)d_ws;
  unsigned short* xh = (unsigned short*)wksp;                   // 8 MB
  unsigned short* xl = xh + (size_t)Q_ * D_;                    // 8 MB
  unsigned short* eh = xl + (size_t)Q_ * D_;                    // 4 MB
  unsigned short* el = eh + (size_t)K_ * D_;                    // 4 MB
  float* e2h = (float*)(el + (size_t)K_ * D_);                  // 32 KB
  unsigned long long* keys = (unsigned long long*)(e2h + K_);   // 128 KB

  prep_x_kernel<<<dim3(N_ / 32, D_ / 32, B_), dim3(32, 8), 0, stream>>>(x, xh, xl);
  prep_e_kernel<<<K_, 256, 0, stream>>>(e, eh, el, e2h, keys);
  vq_main_kernel<<<(Q_ / QTILE_) * KSPLIT_, 512, 0, stream>>>(xh, xl, eh, el, e2h, keys);
  decode_kernel<<<dim3(N_ / 32, B_), dim3(32, 8), 0, stream>>>(keys, e, out);
}